// Round 5
// baseline (209.553 us; speedup 1.0000x reference)
//
#include <hip/hip_runtime.h>

// Problem constants (from setup_inputs): B=4, S=8, T=2048, R=256
#define T_N 2048
#define R_N 256
#define SLICES 32                     // B*S
#define NELEM (SLICES * T_N * R_N)    // 16,777,216 per tensor
#define INFV 3.0e38f
#define MIN_BLOCKS 2048               // 2048 x 256 threads, 8 float4/tensor/thread
#define MIN_THREADS (MIN_BLOCKS * 256)
#define LSTR 2056                     // list stride: 2048 + 8 sentinel slots

// CDF layout: FULL word swizzle (R0-verified). Spreads the data-dependent
// corank/merge b32 probes to ~2 lanes/bank. Sentinels 2048..2055 map to
// themselves ((e>>5)&31 == 64&31 == 0).
#define XS(e) ((e) ^ (((e) >> 5) & 31))
// RAW layout: quad-preserving swizzle. XORs addr bits [4:2] with bits [7:5];
// bits 0,1 intact -> b128 on 4-aligned quads legal and in-order. XQ is an
// involution; 8-spans are NOT contiguous: XQ(8p+4) = XQ(8p)^4 (not +4).
#define XQ(e) ((e) ^ (((e) >> 3) & 28))

// DPP wave-64 min-reduce step (min is order-insensitive -> bit-safe).
#define DPPMIN(x, ctrl, rmask)                                                 \
    fminf((x), __int_as_float(__builtin_amdgcn_update_dpp(                     \
        0x7f800000, __float_as_int(x), (ctrl), (rmask), 0xf, false)))

// Streaming min — R2-verified two-half structure (R4's 16-deep batch
// regressed ~7us, likely VGPR pressure; reverted).
__global__ __launch_bounds__(256) void kmin(const float* __restrict__ x,
                                            const float* __restrict__ y,
                                            float* __restrict__ partial,
                                            float* __restrict__ out) {
    if (blockIdx.x == 0 && threadIdx.x < 4) out[threadIdx.x] = 0.0f;
    const int g0 = blockIdx.x * 256 + threadIdx.x;   // 0..524287
    const float4* __restrict__ x4 = (const float4*)x;
    const float4* __restrict__ y4 = (const float4*)y;
    float m0 = INFV, m1 = INFV;
    #pragma unroll
    for (int half = 0; half < 2; ++half) {
        float4 va[4], vb[4];
        #pragma unroll
        for (int it = 0; it < 4; ++it) {
            const int idx = g0 + (half * 4 + it) * MIN_THREADS;
            va[it] = x4[idx];
            vb[it] = y4[idx];
        }
        #pragma unroll
        for (int it = 0; it < 4; ++it) {
            m0 = fminf(m0, fminf(fminf(va[it].x, va[it].y), fminf(va[it].z, va[it].w)));
            m1 = fminf(m1, fminf(fminf(vb[it].x, vb[it].y), fminf(vb[it].z, vb[it].w)));
        }
    }
    float m = fminf(m0, m1);
    #pragma unroll
    for (int off = 32; off; off >>= 1) m = fminf(m, __shfl_down(m, off));
    __shared__ float sm[4];
    if ((threadIdx.x & 63) == 0) sm[threadIdx.x >> 6] = m;
    __syncthreads();
    if (threadIdx.x == 0)
        partial[blockIdx.x] = fminf(fminf(sm[0], sm[1]), fminf(sm[2], sm[3]));
}

// 1024-thread block = 4 problems, 4 waves/problem. R5: the lane's merged
// window [16pl,16pl+16) is split into two INDEPENDENT 8-step chains
// (coranks at d and d+8, searches interleaved, merges interleaved) to halve
// the serial LDS-latency chain that R4 showed to be the limiter. Merge-path
// property with the same <= tie-break guarantees chain B's start state ==
// chain A's end state, so all segment values are bit-identical; only the
// final accA+accB association differs (<<1e-4 threshold).
__global__ __launch_bounds__(1024, 8) void kmain(const float* __restrict__ x,
                                                 const float* __restrict__ y,
                                                 const float* __restrict__ partial,
                                                 float* __restrict__ out) {
    __shared__ __align__(16) float L[8 * LSTR];  // problem p: U at (2p)*LSTR, V at (2p+1)*LSTR
    __shared__ __align__(16) float red16[16];
    __shared__ __align__(16) float psum[4][2][4];  // [problem][list][wave-chunk]
    __shared__ __align__(16) float pacc[4][4];     // [problem][wave]

    const int tid = threadIdx.x;
    const int w = tid >> 6;           // wave 0..15
    const int lane = tid & 63;

    // ---- XCD-aware remap: 4 blocks sharing a 64B global line -> same XCD ----
    const int blk = blockIdx.x;
    const int xcd = blk & 7;
    const int k2 = blk >> 3;
    const int sub = k2 & 3;
    const int rest = k2 >> 2;
    const int rt = (((rest & 1) << 3) + xcd) * 4 + sub;   // 0..63
    const int bs = rest >> 1;                              // 0..31
    const size_t base = (size_t)bs * (T_N * R_N) + (size_t)(rt * 4);

    // ---- staging loads EARLY (independent of sh): by-tensor split ----
    const int st = tid & 511;
    const int r0 = st << 2;                        // rows r0..r0+3
    const int lb = tid >> 9;                       // 0 = x-lists, 1 = y-lists
    const float* __restrict__ src = (lb == 0) ? x : y;
    const float4 g0v = *(const float4*)(src + base + (size_t)(r0 + 0) * R_N);
    const float4 g1v = *(const float4*)(src + base + (size_t)(r0 + 1) * R_N);
    const float4 g2v = *(const float4*)(src + base + (size_t)(r0 + 2) * R_N);
    const float4 g3v = *(const float4*)(src + base + (size_t)(r0 + 3) * R_N);

    // ---- phase 0: global min (partial[2048]) via DPP ----
    {
        float m = fminf(partial[tid], partial[tid + 1024]);
        m = DPPMIN(m, 0x111, 0xf);    // row_shr:1
        m = DPPMIN(m, 0x112, 0xf);    // row_shr:2
        m = DPPMIN(m, 0x114, 0xf);    // row_shr:4
        m = DPPMIN(m, 0x118, 0xf);    // row_shr:8
        m = DPPMIN(m, 0x142, 0xa);    // row_bcast:15 -> rows 1,3
        m = DPPMIN(m, 0x143, 0xc);    // row_bcast:31 -> rows 2,3
        if (lane == 63) red16[w] = m;
    }
    // ---- sentinels: logical 2048..2055 (identity in XS layout) = INF ----
    if (tid < 64) L[(tid >> 3) * LSTR + T_N + (tid & 7)] = INFV;
    __syncthreads();
    const float4 q0 = *(const float4*)&red16[0];
    const float4 q1 = *(const float4*)&red16[4];
    const float4 q2 = *(const float4*)&red16[8];
    const float4 q3 = *(const float4*)&red16[12];
    const float mn =
        fminf(fminf(fminf(fminf(q0.x, q0.y), fminf(q0.z, q0.w)),
                    fminf(fminf(q1.x, q1.y), fminf(q1.z, q1.w))),
              fminf(fminf(fminf(q2.x, q2.y), fminf(q2.z, q2.w)),
                    fminf(fminf(q3.x, q3.y), fminf(q3.z, q3.w))));
    const float sh = 1.1f * fminf(mn, 0.0f);

    // ---- staging: b128 quad writes into XQ raw layout ----
    {
        const int wq = r0 ^ ((r0 >> 3) & 28);      // XQ(r0); quad-preserved
        *(float4*)&L[(0 + lb) * LSTR + wq] =
            make_float4(g0v.x - sh, g1v.x - sh, g2v.x - sh, g3v.x - sh);
        *(float4*)&L[(2 + lb) * LSTR + wq] =
            make_float4(g0v.y - sh, g1v.y - sh, g2v.y - sh, g3v.y - sh);
        *(float4*)&L[(4 + lb) * LSTR + wq] =
            make_float4(g0v.z - sh, g1v.z - sh, g2v.z - sh, g3v.z - sh);
        *(float4*)&L[(6 + lb) * LSTR + wq] =
            make_float4(g0v.w - sh, g1v.w - sh, g2v.w - sh, g3v.w - sh);
    }
    __syncthreads();

    const int p  = w >> 2;            // problem 0..3
    const int wl = w & 3;             // wave within problem
    const int pl = (wl << 6) | lane;  // problem-lane 0..255
    float* __restrict__ cu = &L[(2 * p) * LSTR];
    float* __restrict__ cv = &L[(2 * p + 1) * LSTR];

    // ---- scan: lane owns logical [8*pl, 8*pl+8) ----
    {
        const int rq = (8 * pl) ^ (pl & 28);       // XQ(8*pl); 2nd quad at rq^4
        float uu[8], vv8[8];
        {
            const float4 t0 = *(const float4*)&cu[rq];
            const float4 t1 = *(const float4*)&cu[rq ^ 4];
            uu[0] = t0.x; uu[1] = t0.y; uu[2] = t0.z; uu[3] = t0.w;
            uu[4] = t1.x; uu[5] = t1.y; uu[6] = t1.z; uu[7] = t1.w;
        }
        float su = 0.f, sv = 0.f;
        #pragma unroll
        for (int k = 0; k < 8; ++k) su += uu[k];
        {
            const float4 t0 = *(const float4*)&cv[rq];
            const float4 t1 = *(const float4*)&cv[rq ^ 4];
            vv8[0] = t0.x; vv8[1] = t0.y; vv8[2] = t0.z; vv8[3] = t0.w;
            vv8[4] = t1.x; vv8[5] = t1.y; vv8[6] = t1.z; vv8[7] = t1.w;
        }
        #pragma unroll
        for (int k = 0; k < 8; ++k) sv += vv8[k];
        float iu = su, iv = sv;
        #pragma unroll
        for (int off = 1; off < 64; off <<= 1) {
            const float a = __shfl_up(iu, off);
            const float b = __shfl_up(iv, off);
            if (lane >= off) { iu += a; iv += b; }
        }
        if (lane == 63) { psum[p][0][wl] = iu; psum[p][1][wl] = iv; }
        __syncthreads();
        const float4 pu4 = *(const float4*)&psum[p][0][0];
        const float4 pv4 = *(const float4*)&psum[p][1][0];
        const float puA[4] = {pu4.x, pu4.y, pu4.z, pu4.w};
        const float pvA[4] = {pv4.x, pv4.y, pv4.z, pv4.w};
        float prefU = 0.f, totU = 0.f, prefV = 0.f, totV = 0.f;
        #pragma unroll
        for (int k = 0; k < 4; ++k) {
            totU += puA[k]; totV += pvA[k];
            if (k < wl) { prefU += puA[k]; prefV += pvA[k]; }
        }
        const float invU = 1.0f / totU, invV = 1.0f / totV;
        float ru = prefU + (iu - su);
        float rv = prefV + (iv - sv);
        const int cm = (pl >> 2) & 31;             // XS mask, hoisted
        #pragma unroll
        for (int k = 0; k < 8; ++k) { ru += uu[k];  cu[(8 * pl + k) ^ cm] = ru * invU; }
        #pragma unroll
        for (int k = 0; k < 8; ++k) { rv += vv8[k]; cv[(8 * pl + k) ^ cm] = rv * invV; }
    }
    __syncthreads();

    // ---- dual co-rank: boundaries d0 = 16*pl and d1 = d0+8, interleaved ----
    // Fixed 11 predicated iterations each (W <= 2048 -> ceil(log2) = 11);
    // the two probe chains overlap their LDS latencies.
    const int d0 = pl << 4;
    const int d1 = d0 + 8;
    int lo0 = (d0 > T_N) ? (d0 - T_N) : 0;
    int hi0 = (d0 < T_N) ? d0 : T_N;
    int lo1 = (d1 > T_N) ? (d1 - T_N) : 0;
    int hi1 = (d1 < T_N) ? d1 : T_N;
    #pragma unroll
    for (int it = 0; it < 11; ++it) {
        const bool a0 = lo0 < hi0;
        const bool a1 = lo1 < hi1;
        const int m0 = (lo0 + hi0) >> 1;
        const int m1 = (lo1 + hi1) >> 1;
        const float u0 = cu[XS(m0)];
        const float w0 = cv[XS(d0 - m0 - 1 >= 0 ? d0 - m0 - 1 : 0)];
        const float u1 = cu[XS(m1)];
        const float w1 = cv[XS(d1 - m1 - 1 >= 0 ? d1 - m1 - 1 : 0)];
        if (a0) { if (u0 <= w0) lo0 = m0 + 1; else hi0 = m0; }
        if (a1) { if (u1 <= w1) lo1 = m1 + 1; else hi1 = m1; }
    }
    // chain A state (positions [d0, d0+8))
    int iA = lo0, jA = d0 - lo0;
    float qpA = 0.0f;
    if (d0 > 0) {
        const float pa_ = (iA > 0) ? cu[XS(iA - 1)] : -INFV;
        const float pb_ = (jA > 0) ? cv[XS(jA - 1)] : -INFV;
        qpA = fmaxf(pa_, pb_);
    }
    // chain B state (positions [d1, d1+8)); d1 >= 8 > 0 always
    int iB = lo1, jB = d1 - lo1;
    float qpB;
    {
        const float pa_ = (iB > 0) ? cu[XS(iB - 1)] : -INFV;
        const float pb_ = (jB > 0) ? cv[XS(jB - 1)] : -INFV;
        qpB = fmaxf(pa_, pb_);
    }

    // ---- merge: two independent 8-step chains, interleaved ----
    float uvA = cu[XS(iA)], vvA = cv[XS(jA)];
    float uvB = cu[XS(iB)], vvB = cv[XS(jB)];
    float accA = 0.0f, accB = 0.0f;
    #pragma unroll
    for (int s = 0; s < 8; ++s) {
        // chain A
        {
            const bool take = (uvA <= vvA);
            const float q = fminf(uvA, vvA);
            const float dd = (float)(min(iA, T_N - 1) - min(jA, T_N - 1));
            accA += (q - qpA) * dd * dd;
            qpA = q;
            iA += take ? 1 : 0;
            jA += take ? 0 : 1;
            if (s < 7) {
                const int ni = take ? iA : jA;
                const float* bp = take ? cu : cv;
                const float r = bp[XS(ni)];
                uvA = take ? r : uvA;
                vvA = take ? vvA : r;
            }
        }
        // chain B (independent of A)
        {
            const bool take = (uvB <= vvB);
            const float q = fminf(uvB, vvB);
            const float dd = (float)(min(iB, T_N - 1) - min(jB, T_N - 1));
            accB += (q - qpB) * dd * dd;
            qpB = q;
            iB += take ? 1 : 0;
            jB += take ? 0 : 1;
            if (s < 7) {
                const int ni = take ? iB : jB;
                const float* bp = take ? cu : cv;
                const float r = bp[XS(ni)];
                uvB = take ? r : uvB;
                vvB = take ? vvB : r;
            }
        }
    }
    float acc = accA + accB;

    // ---- reduce: wave -> LDS -> one atomic per block (order preserved) ----
    #pragma unroll
    for (int off = 32; off; off >>= 1) acc += __shfl_down(acc, off);
    if (lane == 0) pacc[p][wl] = acc;
    __syncthreads();
    if (tid == 0) {
        float r = 0.f;
        #pragma unroll
        for (int pp = 0; pp < 4; ++pp) {
            const float4 pa4 = *(const float4*)&pacc[pp][0];
            r += (pa4.x + pa4.y) + (pa4.z + pa4.w);
        }
        atomicAdd(&out[bs >> 3], r * (1.0f / ((float)T_N * (float)T_N)));
    }
}

extern "C" void kernel_launch(void* const* d_in, const int* in_sizes, int n_in,
                              void* d_out, int out_size, void* d_ws, size_t ws_size,
                              hipStream_t stream) {
    const float* x = (const float*)d_in[0];
    const float* y = (const float*)d_in[1];
    float* out = (float*)d_out;
    float* partial = (float*)d_ws;   // MIN_BLOCKS floats (8 KiB)

    kmin<<<MIN_BLOCKS, 256, 0, stream>>>(x, y, partial, out);
    kmain<<<SLICES * 64, 1024, 0, stream>>>(x, y, partial, out);
}

// Round 6
// 202.245 us; speedup vs baseline: 1.0361x; 1.0361x over previous
//
#include <hip/hip_runtime.h>

// Problem constants (from setup_inputs): B=4, S=8, T=2048, R=256
#define T_N 2048
#define R_N 256
#define SLICES 32                     // B*S
#define NELEM (SLICES * T_N * R_N)    // 16,777,216 per tensor
#define INFV 3.0e38f
#define MIN_BLOCKS 2048               // 2048 x 256 threads, 8 float4/tensor/thread
#define MIN_THREADS (MIN_BLOCKS * 256)
#define LSTR 2056                     // list stride: 2048 + 8 sentinel slots

// Pair-preserving XOR bank swizzle (R2-verified): logical word e ->
// e ^ ((e>>4)&30). Bit 0 preserved -> b64 pair access legal. Sentinels
// 2048..2055 map to themselves.
#define XS(e) ((e) ^ (((e) >> 4) & 30))

// DPP wave-64 min-reduce step (min is order-insensitive -> bit-safe).
#define DPPMIN(x, ctrl, rmask)                                                 \
    fminf((x), __int_as_float(__builtin_amdgcn_update_dpp(                     \
        0x7f800000, __float_as_int(x), (ctrl), (rmask), 0xf, false)))

// DPP wave-64 add step: x += dpp_moved(x), masked-off/invalid lanes add 0.
// VALU-pipe only: replaces ds_bpermute-based __shfl (LDS pipe + lgkmcnt).
#define DPPADDF(x, ctrl, rmask)                                                \
    x += __int_as_float(__builtin_amdgcn_update_dpp(                           \
        0, __float_as_int(x), (ctrl), (rmask), 0xf, false))

// Wave-64 inclusive prefix sum into x; lane 63 ends with the wave total.
// Same control sequence as the verified phase-0 DPPMIN reduce.
#define DPPSCAN(x)                                                             \
    do {                                                                       \
        DPPADDF(x, 0x111, 0xf);   /* row_shr:1  */                             \
        DPPADDF(x, 0x112, 0xf);   /* row_shr:2  */                             \
        DPPADDF(x, 0x114, 0xf);   /* row_shr:4  */                             \
        DPPADDF(x, 0x118, 0xf);   /* row_shr:8  */                             \
        DPPADDF(x, 0x142, 0xa);   /* row_bcast:15 -> rows 1,3 */               \
        DPPADDF(x, 0x143, 0xc);   /* row_bcast:31 -> rows 2,3 */               \
    } while (0)

// Deep-ILP streaming min (R2-verified two-half structure).
__global__ __launch_bounds__(256) void kmin(const float* __restrict__ x,
                                            const float* __restrict__ y,
                                            float* __restrict__ partial,
                                            float* __restrict__ out) {
    if (blockIdx.x == 0 && threadIdx.x < 4) out[threadIdx.x] = 0.0f;
    const int g0 = blockIdx.x * 256 + threadIdx.x;   // 0..524287
    const float4* __restrict__ x4 = (const float4*)x;
    const float4* __restrict__ y4 = (const float4*)y;
    float m0 = INFV, m1 = INFV;
    #pragma unroll
    for (int half = 0; half < 2; ++half) {
        float4 va[4], vb[4];
        #pragma unroll
        for (int it = 0; it < 4; ++it) {
            const int idx = g0 + (half * 4 + it) * MIN_THREADS;
            va[it] = x4[idx];
            vb[it] = y4[idx];
        }
        #pragma unroll
        for (int it = 0; it < 4; ++it) {
            m0 = fminf(m0, fminf(fminf(va[it].x, va[it].y), fminf(va[it].z, va[it].w)));
            m1 = fminf(m1, fminf(fminf(vb[it].x, vb[it].y), fminf(vb[it].z, vb[it].w)));
        }
    }
    float m = fminf(m0, m1);
    #pragma unroll
    for (int off = 32; off; off >>= 1) m = fminf(m, __shfl_down(m, off));
    __shared__ float sm[4];
    if ((threadIdx.x & 63) == 0) sm[threadIdx.x >> 6] = m;
    __syncthreads();
    if (threadIdx.x == 0)
        partial[blockIdx.x] = fminf(fminf(sm[0], sm[1]), fminf(sm[2], sm[3]));
}

// 1024-thread block = 4 problems, 4 waves/problem — the R2-verified kernel
// (best measured: 61.5us) with ONE change-set: all __shfl (ds_bpermute,
// LDS pipe + serial lgkmcnt waits) replaced by DPP adds (VALU pipe, no
// waits): 12 removed from the scan, 6 from the final reduce. The kernel is
// combined-issue-bound (R4/R5 evidence), so shifting issue off the LDS
// pipe at zero VALU cost is the remaining free move. DPP trees reassociate
// the sums: absmax moves off 0.0 to ~1e-7 (threshold 1.9e-4).
__global__ __launch_bounds__(1024, 8) void kmain(const float* __restrict__ x,
                                                 const float* __restrict__ y,
                                                 const float* __restrict__ partial,
                                                 float* __restrict__ out) {
    __shared__ __align__(16) float L[8 * LSTR];  // problem p: U at (2p)*LSTR, V at (2p+1)*LSTR
    __shared__ float red16[16];
    __shared__ float psum[4][2][4];   // [problem][list][wave-chunk] scan partials
    __shared__ float pacc[4][4];      // [problem][wave] result partials

    const int tid = threadIdx.x;
    const int w = tid >> 6;           // wave 0..15
    const int lane = tid & 63;

    // ---- XCD-aware remap: 4 blocks sharing a 64B global line -> same XCD ----
    const int blk = blockIdx.x;
    const int xcd = blk & 7;
    const int k2 = blk >> 3;
    const int sub = k2 & 3;
    const int rest = k2 >> 2;
    const int rt = (((rest & 1) << 3) + xcd) * 4 + sub;   // 0..63
    const int bs = rest >> 1;                              // 0..31
    const size_t base = (size_t)bs * (T_N * R_N) + (size_t)(rt * 4);

    // ---- issue staging loads EARLY (independent of sh): rows 2tid, 2tid+1 ----
    const int r0 = tid << 1;
    const float4 a0 = *(const float4*)(x + base + (size_t)r0 * R_N);
    const float4 a1 = *(const float4*)(x + base + (size_t)(r0 + 1) * R_N);
    const float4 b0 = *(const float4*)(y + base + (size_t)r0 * R_N);
    const float4 b1 = *(const float4*)(y + base + (size_t)(r0 + 1) * R_N);

    // ---- phase 0: global min (partial[2048]) via DPP ----
    {
        float m = fminf(partial[tid], partial[tid + 1024]);
        m = DPPMIN(m, 0x111, 0xf);    // row_shr:1
        m = DPPMIN(m, 0x112, 0xf);    // row_shr:2
        m = DPPMIN(m, 0x114, 0xf);    // row_shr:4
        m = DPPMIN(m, 0x118, 0xf);    // row_shr:8
        m = DPPMIN(m, 0x142, 0xa);    // row_bcast:15 -> rows 1,3
        m = DPPMIN(m, 0x143, 0xc);    // row_bcast:31 -> rows 2,3
        if (lane == 63) red16[w] = m; // lane 63 holds the wave min
    }
    // ---- sentinels: logical 2048..2055 (swizzle-identity) = INF ----
    if (tid < 64) L[(tid >> 3) * LSTR + T_N + (tid & 7)] = INFV;
    __syncthreads();
    float mn = red16[0];
    #pragma unroll
    for (int k = 1; k < 16; ++k) mn = fminf(mn, red16[k]);
    const float sh = 1.1f * fminf(mn, 0.0f);

    // ---- staging: b64 swizzled pair writes (elements 2tid, 2tid+1) ----
    {
        const int ws_ = XS(r0);       // even -> 8B-aligned
        *(float2*)&L[0 * LSTR + ws_] = make_float2(a0.x - sh, a1.x - sh);
        *(float2*)&L[2 * LSTR + ws_] = make_float2(a0.y - sh, a1.y - sh);
        *(float2*)&L[4 * LSTR + ws_] = make_float2(a0.z - sh, a1.z - sh);
        *(float2*)&L[6 * LSTR + ws_] = make_float2(a0.w - sh, a1.w - sh);
        *(float2*)&L[1 * LSTR + ws_] = make_float2(b0.x - sh, b1.x - sh);
        *(float2*)&L[3 * LSTR + ws_] = make_float2(b0.y - sh, b1.y - sh);
        *(float2*)&L[5 * LSTR + ws_] = make_float2(b0.z - sh, b1.z - sh);
        *(float2*)&L[7 * LSTR + ws_] = make_float2(b0.w - sh, b1.w - sh);
    }
    __syncthreads();

    const int p  = w >> 2;            // problem 0..3
    const int wl = w & 3;             // wave within problem
    const int pl = (wl << 6) | lane;  // problem-lane 0..255
    float* __restrict__ cu = &L[(2 * p) * LSTR];
    float* __restrict__ cv = &L[(2 * p + 1) * LSTR];

    // ---- scan: lane owns logical [8*pl, 8*pl+8), b64 pair access ----
    {
        int offp[4];
        #pragma unroll
        for (int c = 0; c < 4; ++c) offp[c] = XS(8 * pl + 2 * c);
        float uu[8], vv8[8];
        float su = 0.f, sv = 0.f;
        #pragma unroll
        for (int c = 0; c < 4; ++c) {
            const float2 t2 = *(const float2*)&cu[offp[c]];
            uu[2 * c] = t2.x; uu[2 * c + 1] = t2.y;
        }
        #pragma unroll
        for (int k = 0; k < 8; ++k) su += uu[k];
        #pragma unroll
        for (int c = 0; c < 4; ++c) {
            const float2 t2 = *(const float2*)&cv[offp[c]];
            vv8[2 * c] = t2.x; vv8[2 * c + 1] = t2.y;
        }
        #pragma unroll
        for (int k = 0; k < 8; ++k) sv += vv8[k];
        // wave-64 inclusive prefix via DPP (VALU pipe; replaces 12 shfl_up)
        float iu = su, iv = sv;
        DPPSCAN(iu);
        DPPSCAN(iv);
        if (lane == 63) { psum[p][0][wl] = iu; psum[p][1][wl] = iv; }
        __syncthreads();
        float prefU = 0.f, totU = 0.f, prefV = 0.f, totV = 0.f;
        #pragma unroll
        for (int k = 0; k < 4; ++k) {
            const float a = psum[p][0][k], b = psum[p][1][k];
            totU += a; totV += b;
            if (k < wl) { prefU += a; prefV += b; }
        }
        const float invU = 1.0f / totU, invV = 1.0f / totV;
        float ru = prefU + (iu - su);
        float rv = prefV + (iv - sv);
        #pragma unroll
        for (int c = 0; c < 4; ++c) {
            const float ra = ru + uu[2 * c];
            const float rb = ra + uu[2 * c + 1];
            ru = rb;
            *(float2*)&cu[offp[c]] = make_float2(ra * invU, rb * invU);
        }
        #pragma unroll
        for (int c = 0; c < 4; ++c) {
            const float ra = rv + vv8[2 * c];
            const float rb = ra + vv8[2 * c + 1];
            rv = rb;
            *(float2*)&cv[offp[c]] = make_float2(ra * invV, rb * invV);
        }
    }
    __syncthreads();

    // ---- co-rank partition: lane handles merged window [16*pl, 16*pl+16) ----
    const int d = pl << 4;
    int i = 0, j = 0;
    if (d > 0) {
        int lo = (d > T_N) ? (d - T_N) : 0;
        int hi = (d < T_N) ? d : T_N;
        while (lo < hi) {
            const int mid = (lo + hi) >> 1;
            if (cu[XS(mid)] <= cv[XS(d - mid - 1)]) lo = mid + 1; else hi = mid;
        }
        i = lo; j = d - lo;
    }
    float qprev = 0.0f;
    if (d > 0) {
        const float pa_ = (i > 0) ? cu[XS(i - 1)] : -INFV;
        const float pb_ = (j > 0) ? cv[XS(j - 1)] : -INFV;
        qprev = fmaxf(pa_, pb_);
    }

    // ---- merge: 16 steps, refill only the advanced list, sentinel-direct ----
    float uv = cu[XS(i)];
    float vv = cv[XS(j)];
    float acc = 0.0f;
    #pragma unroll
    for (int s = 0; s < 16; ++s) {
        const bool take = (uv <= vv);
        const float q = fminf(uv, vv);
        const float dd = (float)(min(i, T_N - 1) - min(j, T_N - 1));
        acc += (q - qprev) * dd * dd;
        qprev = q;
        i += take ? 1 : 0;
        j += take ? 0 : 1;
        if (s < 15) {
            const int ni = take ? i : j;           // advanced index (<= 2048)
            const float* bp = take ? cu : cv;
            const float r = bp[XS(ni)];
            uv = take ? r : uv;
            vv = take ? vv : r;
        }
    }

    // ---- reduce: wave total via DPP (lane 63) -> LDS -> one atomic ----
    DPPSCAN(acc);
    if (lane == 63) pacc[p][wl] = acc;
    __syncthreads();
    if (tid == 0) {
        float r = 0.f;
        #pragma unroll
        for (int pp = 0; pp < 4; ++pp)
            r += (pacc[pp][0] + pacc[pp][1]) + (pacc[pp][2] + pacc[pp][3]);
        atomicAdd(&out[bs >> 3], r * (1.0f / ((float)T_N * (float)T_N)));
    }
}

extern "C" void kernel_launch(void* const* d_in, const int* in_sizes, int n_in,
                              void* d_out, int out_size, void* d_ws, size_t ws_size,
                              hipStream_t stream) {
    const float* x = (const float*)d_in[0];
    const float* y = (const float*)d_in[1];
    float* out = (float*)d_out;
    float* partial = (float*)d_ws;   // MIN_BLOCKS floats (8 KiB)

    kmin<<<MIN_BLOCKS, 256, 0, stream>>>(x, y, partial, out);
    kmain<<<SLICES * 64, 1024, 0, stream>>>(x, y, partial, out);
}